// Round 7
// baseline (376.453 us; speedup 1.0000x reference)
//
#include <hip/hip_runtime.h>
#include <stdint.h>

#define LEAKY 0.2f
#define NB 32768
#define HD 256

typedef __attribute__((ext_vector_type(8))) short short8;
typedef __attribute__((ext_vector_type(8))) unsigned short ushort8;
typedef __attribute__((ext_vector_type(4))) float f4;

static __device__ __forceinline__ float bf2f(unsigned short u) {
  union { unsigned int i; float f; } v; v.i = ((unsigned int)u) << 16; return v.f;
}
static __device__ __forceinline__ unsigned short f2bf(float f) {
  union { float f; unsigned int i; } v; v.f = f;
  return (unsigned short)((v.i + 0x7fffu + ((v.i >> 16) & 1u)) >> 16);  // RNE
}
static __device__ __forceinline__ ushort8 pack8(f4 a, f4 b) {
  ushort8 o;
  o[0] = f2bf(a[0]); o[1] = f2bf(a[1]); o[2] = f2bf(a[2]); o[3] = f2bf(a[3]);
  o[4] = f2bf(b[0]); o[5] = f2bf(b[1]); o[6] = f2bf(b[2]); o[7] = f2bf(b[3]);
  return o;
}
static __device__ __forceinline__ float sigm(float x) { return 1.f / (1.f + __expf(-x)); }
static __device__ __forceinline__ float tanha(float x) {
  float e = __expf(2.f * x);
  return 1.f - 2.f / (e + 1.f);   // finite for e -> inf
}

__device__ __forceinline__ void gload16(const void* g, void* s) {
  __builtin_amdgcn_global_load_lds(
      (const __attribute__((address_space(1))) unsigned int*)g,
      (__attribute__((address_space(3))) unsigned int*)s, 16, 0, 0);
}

// ---------------- weight prep: LDS-tiled transpose, 1 launch ----------------
__global__ void wprep(const float* __restrict__ W1, const float* __restrict__ W2,
                      const float* __restrict__ W3, const float* __restrict__ Wk,
                      const float* __restrict__ Wr,
                      unsigned short* __restrict__ W1t, unsigned short* __restrict__ W2t,
                      unsigned short* __restrict__ W3t, unsigned short* __restrict__ Wkrt) {
  __shared__ float tile[64][65];
  const int id = blockIdx.x, t = threadIdx.x;
  const int tr = t >> 6, tc = t & 63;   // 4 rows per pass, 16 passes

  const float* src;
  unsigned short* dst;
  int kbase, nbase, srcld, perm = 0;
  if (id < 64) {
    src = W1; dst = W1t; srcld = 512;
    kbase = (id >> 3) * 64; nbase = (id & 7) * 64;
  } else if (id < 128) {
    src = W2; dst = W2t; srcld = 512;
    kbase = ((id - 64) >> 3) * 64; nbase = ((id - 64) & 7) * 64;
  } else if (id < 160) {
    src = W3; dst = W3t; srcld = 256;
    kbase = ((id - 128) >> 2) * 64; nbase = ((id - 128) & 3) * 64;
  } else {
    src = nullptr; dst = Wkrt; srcld = 1024; perm = 1;
    kbase = ((id - 160) >> 4) * 64; nbase = ((id - 160) & 15) * 64;
  }

#pragma unroll
  for (int p = 0; p < 16; ++p) {
    int r = p * 4 + tr;             // k offset within tile
    int k = kbase + r, n = nbase + tc;
    float v;
    if (perm) {
      v = (k < 256) ? Wk[k * 1024 + n] : Wr[(k - 256) * 1024 + n];
    } else {
      v = src[k * srcld + n];
    }
    tile[r][tc] = v;
  }
  __syncthreads();
#pragma unroll
  for (int p = 0; p < 16; ++p) {
    int c = p * 4 + tr;             // n offset within tile
    int n = nbase + c;
    int orow;
    if (perm) {
      int gate = n >> 8, hcol = n & 255;
      orow = (hcol >> 5) * 128 + ((hcol >> 4) & 1) * 64 + gate * 16 + (hcol & 15);
    } else {
      orow = n;
    }
    dst[orow * 512 + kbase + tc] = f2bf(tile[tc][c]);
  }
}

// catb[:, :256] = bf16(x); csb[:, :256] = bf16(h); csb[:, 256:] = bf16(gather(h, vid))
__global__ void build_rows(const float* __restrict__ x, const float* __restrict__ h,
                           const int* __restrict__ vid,
                           unsigned short* __restrict__ catb,
                           unsigned short* __restrict__ csb) {
  int idx = blockIdx.x * 256 + threadIdx.x;   // NB*32 threads, 8 elems each
  int m = idx >> 5;
  int j = (idx & 31) << 3;
  f4 a0 = *(const f4*)(x + (size_t)m * 256 + j);
  f4 a1 = *(const f4*)(x + (size_t)m * 256 + j + 4);
  *(ushort8*)(catb + (size_t)m * 512 + j) = pack8(a0, a1);
  f4 h0 = *(const f4*)(h + (size_t)m * 256 + j);
  f4 h1 = *(const f4*)(h + (size_t)m * 256 + j + 4);
  *(ushort8*)(csb + (size_t)m * 512 + j) = pack8(h0, h1);
  int id = vid[m];
  f4 g0 = {0.f, 0.f, 0.f, 0.f}, g1 = {0.f, 0.f, 0.f, 0.f};
  if (id >= 0) {
    g0 = *(const f4*)(h + (size_t)id * 256 + j);
    g1 = *(const f4*)(h + (size_t)id * 256 + j + 4);
  }
  *(ushort8*)(csb + (size_t)m * 512 + 256 + j) = pack8(g0, g1);
}

// ------------- 256x256-tile GEMM, counted-vmcnt double-buffer pipeline -------------
// epilogue(A[M,512] @ Bt[N,512]^T + bias). 512 thr / 8 waves (2M x 4N), wave = 128x64.
// Per K-tile (BK=64): vmcnt(8) [tile t+1 stays in flight] -> barrier -> compute ->
// barrier -> stage tile t+2 into freed slot. Raw s_barrier (no vmcnt(0) drain).
// MODE 0: leaky -> bf16. MODE 1: leaky + final_h -> f32 + bf16. MODE 3: fused LSTM.
template <int MODE, int NTN>
__global__ __launch_bounds__(512, 2) void gemm256(
    const unsigned short* __restrict__ A,   // [M, 512] bf16 row-major
    const unsigned short* __restrict__ Bt,  // [N, 512] bf16 row-major
    const float* __restrict__ bias,
    unsigned short* __restrict__ outb, int ldo, int col_off,
    float* __restrict__ outf,               // MODE1: f32 final_h; MODE3: d_out base
    const float* __restrict__ hst,          // MODE1: h
    const int* __restrict__ vid,            // MODE1
    const float* __restrict__ cin,          // MODE3: c
    const unsigned char* __restrict__ rsp) {// MODE3: real_step
  __shared__ unsigned short sA[2][256 * 64];   // 2 x 32 KB
  __shared__ unsigned short sB[2][256 * 64];   // 2 x 32 KB  (total 128 KB)

  const int t = threadIdx.x;
  const int p = blockIdx.x;
  const int xcd = p & 7, local = p >> 3;
  const int tm = xcd + ((local / NTN) << 3);   // all NTN col-tiles of a row-tile on 1 XCD
  const int tn = local % NTN;
  const int wid = t >> 6, lane = t & 63;
  const int wr = wid >> 2, wcn = wid & 3;      // wave = rows [wr*128,+128) x cols [wcn*64,+64)
  const int lrow = lane & 15, lkhi = lane >> 4;
  const int rsub8 = t >> 3, slot8 = t & 7;

  const unsigned short* Asrc = A + (size_t)tm * 256 * 512;
  const unsigned short* Bsrc = Bt + (size_t)tn * 256 * 512;

#define STAGE(kt, s)                                                              \
  {                                                                               \
    _Pragma("unroll") for (int i_ = 0; i_ < 4; ++i_) {                            \
      int r_ = i_ * 64 + rsub8;                                                   \
      int gs_ = slot8 ^ (r_ & 7);                                                 \
      gload16(Asrc + (size_t)r_ * 512 + (kt) * 64 + gs_ * 8,                      \
              (char*)&sA[s][0] + r_ * 128 + slot8 * 16);                          \
      gload16(Bsrc + (size_t)r_ * 512 + (kt) * 64 + gs_ * 8,                      \
              (char*)&sB[s][0] + r_ * 128 + slot8 * 16);                          \
    }                                                                             \
  }

  f4 acc[8][4];
#pragma unroll
  for (int i = 0; i < 8; ++i)
#pragma unroll
    for (int j = 0; j < 4; ++j) acc[i][j] = {0.f, 0.f, 0.f, 0.f};

  STAGE(0, 0)
  STAGE(1, 1)

#pragma unroll
  for (int kt = 0; kt < 8; ++kt) {
    const int cur = kt & 1;
    if (kt < 7) {
      asm volatile("s_waitcnt vmcnt(8)" ::: "memory");   // tile kt done; kt+1 in flight
    } else {
      asm volatile("s_waitcnt vmcnt(0)" ::: "memory");
    }
    __builtin_amdgcn_s_barrier();                        // tile kt visible to all waves
    __builtin_amdgcn_sched_barrier(0);
#pragma unroll
    for (int kk = 0; kk < 2; ++kk) {
      short8 bfr[4];
#pragma unroll
      for (int ni = 0; ni < 4; ++ni) {
        int rn = wcn * 64 + ni * 16 + lrow;
        int s = (kk * 4 + lkhi) ^ (rn & 7);
        bfr[ni] = *(const short8*)&sB[cur][rn * 64 + s * 8];
      }
#pragma unroll
      for (int mi = 0; mi < 8; ++mi) {
        int row = wr * 128 + mi * 16 + lrow;
        int s = (kk * 4 + lkhi) ^ (row & 7);
        short8 a = *(const short8*)&sA[cur][row * 64 + s * 8];
#pragma unroll
        for (int ni = 0; ni < 4; ++ni)
          acc[mi][ni] = __builtin_amdgcn_mfma_f32_16x16x32_bf16(a, bfr[ni],
                                                                acc[mi][ni], 0, 0, 0);
      }
    }
    __builtin_amdgcn_s_barrier();                        // all waves done reading slot cur
    __builtin_amdgcn_sched_barrier(0);
    if (kt + 2 < 8) STAGE(kt + 2, cur)                   // refill freed slot; no drain
  }
#undef STAGE

  const int m_base = tm * 256 + wr * 128;
  const int n_base = tn * 256 + wcn * 64;
  if (MODE == 1) {
#pragma unroll
    for (int mi = 0; mi < 8; ++mi) {
#pragma unroll
      for (int r = 0; r < 4; ++r) {
        int row = m_base + mi * 16 + lkhi * 4 + r;
        int id = vid[row];
#pragma unroll
        for (int ni = 0; ni < 4; ++ni) {
          int col = n_base + ni * 16 + lrow;
          float v = acc[mi][ni][r] + bias[col];
          v = v > 0.f ? v : LEAKY * v;
          float hv = hst[(size_t)row * HD + col];
          float fh = (id >= 0) ? hv + v : hv;
          outf[(size_t)row * HD + col] = fh;                       // f32 final_h
          outb[(size_t)row * ldo + col_off + col] = f2bf(fh);      // bf16 for LSTM GEMM
        }
      }
    }
  } else if (MODE == 3) {
    const bool real = rsp[0] != 0;
    const int hcol = (tn * 2 + (wcn >> 1)) * 32 + (wcn & 1) * 16 + lrow;
    const float bi = bias[hcol];
    const float bff = bias[256 + hcol];
    const float bg = bias[512 + hcol];
    const float bo = bias[768 + hcol];
    float* outs = outf;
    float* houtp = outf + (size_t)NB * HD;
    float* coutp = outf + (size_t)2 * NB * HD;
#pragma unroll
    for (int mi = 0; mi < 8; ++mi) {
#pragma unroll
      for (int r = 0; r < 4; ++r) {
        int row = m_base + mi * 16 + lkhi * 4 + r;
        size_t base = (size_t)row * HD + hcol;
        float cold = cin[base];
        float i_ = sigm(acc[mi][0][r] + bi);
        float f_ = sigm(acc[mi][1][r] + bff);
        float g_ = tanha(acc[mi][2][r] + bg);
        float o_ = sigm(acc[mi][3][r] + bo);
        float cv = f_ * cold + i_ * g_;
        float hv = o_ * tanha(cv);
        outs[base] = hv;
        if (real) {
          houtp[base] = hv;       // else: final_h already written by MODE1
          coutp[base] = cv;
        } else {
          coutp[base] = cold;
        }
      }
    }
  } else {  // MODE 0
#pragma unroll
    for (int ni = 0; ni < 4; ++ni) {
      int col = n_base + ni * 16 + lrow;
      float bia = bias[col];
#pragma unroll
      for (int mi = 0; mi < 8; ++mi) {
#pragma unroll
        for (int r = 0; r < 4; ++r) {
          int row = m_base + mi * 16 + lkhi * 4 + r;
          float v = acc[mi][ni][r] + bia;
          v = v > 0.f ? v : LEAKY * v;
          outb[(size_t)row * ldo + col_off + col] = f2bf(v);
        }
      }
    }
  }
}

// ---------------- launch ----------------
extern "C" void kernel_launch(void* const* d_in, const int* in_sizes, int n_in,
                              void* d_out, int out_size, void* d_ws, size_t ws_size,
                              hipStream_t stream) {
  const float* x = (const float*)d_in[0];
  const int* vid = (const int*)d_in[1];
  const unsigned char* rs = (const unsigned char*)d_in[2];
  const float* h = (const float*)d_in[3];
  const float* c = (const float*)d_in[4];
  const float* W1 = (const float*)d_in[5];
  const float* b1 = (const float*)d_in[6];
  const float* W2 = (const float*)d_in[7];
  const float* b2 = (const float*)d_in[8];
  const float* W3 = (const float*)d_in[9];
  const float* b3 = (const float*)d_in[10];
  const float* Wk = (const float*)d_in[11];
  const float* Wr = (const float*)d_in[12];
  const float* bl = (const float*)d_in[13];
  float* dout = (float*)d_out;

  char* ws = (char*)d_ws;
  unsigned short* W1t = (unsigned short*)(ws);                         // 512x512 bf16
  unsigned short* W2t = (unsigned short*)(ws + 524288);                // 512x512
  unsigned short* W3t = (unsigned short*)(ws + 1048576);               // 256x512
  unsigned short* Wkrt = (unsigned short*)(ws + 1310720);              // 1024x512
  unsigned short* bufA = (unsigned short*)(ws + 2359296);              // [B,512] bf16
  unsigned short* bufB = (unsigned short*)(ws + 2359296 + 33554432);   // [B,512] bf16
  unsigned short* catb = (unsigned short*)(ws + 2359296 + 67108864);   // [B,512] bf16

  float* fhout = dout + (size_t)NB * HD;  // h_out slot doubles as f32 final_h

  wprep<<<288, 256, 0, stream>>>(W1, W2, W3, Wk, Wr, W1t, W2t, W3t, Wkrt);
  build_rows<<<NB * 32 / 256, 256, 0, stream>>>(x, h, vid, catb, bufA);

  // L1: bufB = leaky(cs0 @ W1 + b1)
  gemm256<0, 2><<<(NB / 256) * 2, 512, 0, stream>>>(
      bufA, W1t, b1, bufB, 512, 0, nullptr, nullptr, nullptr, nullptr, nullptr);
  // L2: bufA = leaky(a1 @ W2 + b2)
  gemm256<0, 2><<<(NB / 256) * 2, 512, 0, stream>>>(
      bufB, W2t, b2, bufA, 512, 0, nullptr, nullptr, nullptr, nullptr, nullptr);
  // L3: cs = leaky(a2 @ W3 + b3); final_h = h + cs (vid>=0) -> fhout f32 + catb[:,256:]
  gemm256<1, 1><<<(NB / 256) * 1, 512, 0, stream>>>(
      bufA, W3t, b3, catb, 512, 256, fhout, h, vid, nullptr, nullptr);
  // LSTM: z = [x, fh] @ Wkrt^T + bl, gates fused in-register -> outputs/h_out/c_out
  gemm256<3, 4><<<(NB / 256) * 4, 512, 0, stream>>>(
      catb, Wkrt, bl, nullptr, 0, 0, dout, nullptr, nullptr, c, rs);
}

// Round 8
// 363.229 us; speedup vs baseline: 1.0364x; 1.0364x over previous
//
#include <hip/hip_runtime.h>
#include <stdint.h>

#define LEAKY 0.2f
#define NB 32768
#define HD 256

typedef __attribute__((ext_vector_type(8))) short short8;
typedef __attribute__((ext_vector_type(8))) unsigned short ushort8;
typedef __attribute__((ext_vector_type(4))) float f4;

static __device__ __forceinline__ float bf2f(unsigned short u) {
  union { unsigned int i; float f; } v; v.i = ((unsigned int)u) << 16; return v.f;
}
static __device__ __forceinline__ unsigned short f2bf(float f) {
  union { float f; unsigned int i; } v; v.f = f;
  return (unsigned short)((v.i + 0x7fffu + ((v.i >> 16) & 1u)) >> 16);  // RNE
}
static __device__ __forceinline__ ushort8 pack8(f4 a, f4 b) {
  ushort8 o;
  o[0] = f2bf(a[0]); o[1] = f2bf(a[1]); o[2] = f2bf(a[2]); o[3] = f2bf(a[3]);
  o[4] = f2bf(b[0]); o[5] = f2bf(b[1]); o[6] = f2bf(b[2]); o[7] = f2bf(b[3]);
  return o;
}
static __device__ __forceinline__ float sigm(float x) { return 1.f / (1.f + __expf(-x)); }
static __device__ __forceinline__ float tanha(float x) {
  float e = __expf(2.f * x);
  return 1.f - 2.f / (e + 1.f);   // finite for e -> inf
}

__device__ __forceinline__ void gload16(const void* g, void* s) {
  __builtin_amdgcn_global_load_lds(
      (const __attribute__((address_space(1))) unsigned int*)g,
      (__attribute__((address_space(3))) unsigned int*)s, 16, 0, 0);
}

// ---------------- weight prep: LDS-tiled transpose, 1 launch ----------------
__global__ void wprep(const float* __restrict__ W1, const float* __restrict__ W2,
                      const float* __restrict__ W3, const float* __restrict__ Wk,
                      const float* __restrict__ Wr,
                      unsigned short* __restrict__ W1t, unsigned short* __restrict__ W2t,
                      unsigned short* __restrict__ W3t, unsigned short* __restrict__ Wkrt) {
  __shared__ float tile[64][65];
  const int id = blockIdx.x, t = threadIdx.x;
  const int tr = t >> 6, tc = t & 63;   // 4 rows per pass, 16 passes

  const float* src;
  unsigned short* dst;
  int kbase, nbase, srcld, perm = 0;
  if (id < 64) {
    src = W1; dst = W1t; srcld = 512;
    kbase = (id >> 3) * 64; nbase = (id & 7) * 64;
  } else if (id < 128) {
    src = W2; dst = W2t; srcld = 512;
    kbase = ((id - 64) >> 3) * 64; nbase = ((id - 64) & 7) * 64;
  } else if (id < 160) {
    src = W3; dst = W3t; srcld = 256;
    kbase = ((id - 128) >> 2) * 64; nbase = ((id - 128) & 3) * 64;
  } else {
    src = nullptr; dst = Wkrt; srcld = 1024; perm = 1;
    kbase = ((id - 160) >> 4) * 64; nbase = ((id - 160) & 15) * 64;
  }

#pragma unroll
  for (int p = 0; p < 16; ++p) {
    int r = p * 4 + tr;             // k offset within tile
    int k = kbase + r, n = nbase + tc;
    float v;
    if (perm) {
      v = (k < 256) ? Wk[k * 1024 + n] : Wr[(k - 256) * 1024 + n];
    } else {
      v = src[k * srcld + n];
    }
    tile[r][tc] = v;
  }
  __syncthreads();
#pragma unroll
  for (int p = 0; p < 16; ++p) {
    int c = p * 4 + tr;             // n offset within tile
    int n = nbase + c;
    int orow;
    if (perm) {
      int gate = n >> 8, hcol = n & 255;
      orow = (hcol >> 5) * 128 + ((hcol >> 4) & 1) * 64 + gate * 16 + (hcol & 15);
    } else {
      orow = n;
    }
    dst[orow * 512 + kbase + tc] = f2bf(tile[tc][c]);
  }
}

// catb[:, :256] = bf16(x); csb[:, :256] = bf16(h); csb[:, 256:] = bf16(gather(h, vid))
__global__ void build_rows(const float* __restrict__ x, const float* __restrict__ h,
                           const int* __restrict__ vid,
                           unsigned short* __restrict__ catb,
                           unsigned short* __restrict__ csb) {
  int idx = blockIdx.x * 256 + threadIdx.x;   // NB*32 threads, 8 elems each
  int m = idx >> 5;
  int j = (idx & 31) << 3;
  f4 a0 = *(const f4*)(x + (size_t)m * 256 + j);
  f4 a1 = *(const f4*)(x + (size_t)m * 256 + j + 4);
  *(ushort8*)(catb + (size_t)m * 512 + j) = pack8(a0, a1);
  f4 h0 = *(const f4*)(h + (size_t)m * 256 + j);
  f4 h1 = *(const f4*)(h + (size_t)m * 256 + j + 4);
  *(ushort8*)(csb + (size_t)m * 512 + j) = pack8(h0, h1);
  int id = vid[m];
  f4 g0 = {0.f, 0.f, 0.f, 0.f}, g1 = {0.f, 0.f, 0.f, 0.f};
  if (id >= 0) {
    g0 = *(const f4*)(h + (size_t)id * 256 + j);
    g1 = *(const f4*)(h + (size_t)id * 256 + j + 4);
  }
  *(ushort8*)(csb + (size_t)m * 512 + 256 + j) = pack8(g0, g1);
}

// ---- 128x128-tile GEMM, BK=32, 4-slot LDS ring, counted-vmcnt prefetch depth 3 ----
// epilogue(A[M,512] @ Bt[N,512]^T + bias). 256 thr / 4 waves (2x2), wave = 64x64.
// Per iter T (16 iters): vmcnt(8) [tiles T+1,T+2 in flight] -> s_barrier ->
// STAGE(T+3 -> slot (T+3)&3, freed at T-1 and protected by this barrier) ->
// ds_read slot T&3 -> 16 MFMA. One barrier per iter; never drains mid-loop.
// 2 blocks/CU (64 KB LDS) keeps cross-block decorrelation (the round-7 lesson).
// MODE 0: leaky -> bf16. MODE 1: leaky + final_h -> f32 + bf16. MODE 3: fused LSTM.
template <int MODE, int NTN>
__global__ __launch_bounds__(256, 2) void gemm_bk32(
    const unsigned short* __restrict__ A,   // [M, 512] bf16 row-major
    const unsigned short* __restrict__ Bt,  // [N, 512] bf16 row-major
    const float* __restrict__ bias,
    unsigned short* __restrict__ outb, int ldo, int col_off,
    float* __restrict__ outf,               // MODE1: f32 final_h; MODE3: d_out base
    const float* __restrict__ hst,          // MODE1: h
    const int* __restrict__ vid,            // MODE1
    const float* __restrict__ cin,          // MODE3: c
    const unsigned char* __restrict__ rsp) {// MODE3: real_step
  __shared__ unsigned short sA[4][128 * 32];   // 4 x 8 KB
  __shared__ unsigned short sB[4][128 * 32];   // 4 x 8 KB   (64 KB total)

  const int t = threadIdx.x;
  const int p = blockIdx.x;
  const int xcd = p & 7, local = p >> 3;
  const int tm = xcd + ((local / NTN) << 3);   // T1: col-tiles of a row-tile share an XCD
  const int tn = local % NTN;
  const int wid = t >> 6, lane = t & 63;
  const int wr = wid >> 1, wc = wid & 1;       // 2x2 waves -> 64x64 each
  const int lrow = lane & 15, lkhi = lane >> 4;

  const unsigned short* Asrc = A + (size_t)tm * 128 * 512;
  const unsigned short* Bsrc = Bt + (size_t)tn * 128 * 512;

  // staging geometry: 2 passes x (row = idx>>2 in 0..127, 16B k-slot = idx&3)
  const int r0 = t >> 2, sl0 = t & 3;
  const int r1 = (256 + t) >> 2, sl1 = sl0;    // pass 1: rows 64..127, same slot
  const int gs0 = sl0 ^ ((r0 & 3) ^ ((r0 >> 2) & 3));
  const int gs1 = sl1 ^ ((r1 & 3) ^ ((r1 >> 2) & 3));

#define STAGE(kt, s)                                                          \
  {                                                                           \
    gload16(Asrc + (size_t)r0 * 512 + (kt) * 32 + gs0 * 8,                    \
            (char*)&sA[s][0] + t * 16);                                       \
    gload16(Bsrc + (size_t)r0 * 512 + (kt) * 32 + gs0 * 8,                    \
            (char*)&sB[s][0] + t * 16);                                       \
    gload16(Asrc + (size_t)r1 * 512 + (kt) * 32 + gs1 * 8,                    \
            (char*)&sA[s][0] + 4096 + t * 16);                                \
    gload16(Bsrc + (size_t)r1 * 512 + (kt) * 32 + gs1 * 8,                    \
            (char*)&sB[s][0] + 4096 + t * 16);                                \
  }

  f4 acc[4][4];
#pragma unroll
  for (int i = 0; i < 4; ++i)
#pragma unroll
    for (int j = 0; j < 4; ++j) acc[i][j] = {0.f, 0.f, 0.f, 0.f};

  STAGE(0, 0) STAGE(1, 1) STAGE(2, 2)          // 12 loads/wave in flight

#pragma unroll
  for (int T = 0; T < 16; ++T) {
    const int cur = T & 3;
    if (T <= 13) {
      asm volatile("s_waitcnt vmcnt(8)" ::: "memory");   // tile T landed; T+1,T+2 fly
    } else if (T == 14) {
      asm volatile("s_waitcnt vmcnt(4)" ::: "memory");
    } else {
      asm volatile("s_waitcnt vmcnt(0)" ::: "memory");
    }
    __builtin_amdgcn_s_barrier();          // all waves' tile-T loads now LDS-visible
    __builtin_amdgcn_sched_barrier(0);
    if (T + 3 < 16) STAGE(T + 3, (T + 3) & 3)  // slot freed at T-1, fenced by barrier
    __builtin_amdgcn_sched_barrier(0);

    short8 af[4], bfr[4];
#pragma unroll
    for (int mi = 0; mi < 4; ++mi) {
      int row = wr * 64 + mi * 16 + lrow;
      int f = (row & 3) ^ ((row >> 2) & 3);
      af[mi] = *(const short8*)&sA[cur][row * 32 + ((lkhi ^ f) << 3)];
    }
#pragma unroll
    for (int ni = 0; ni < 4; ++ni) {
      int rn = wc * 64 + ni * 16 + lrow;
      int f = (rn & 3) ^ ((rn >> 2) & 3);
      bfr[ni] = *(const short8*)&sB[cur][rn * 32 + ((lkhi ^ f) << 3)];
    }
#pragma unroll
    for (int mi = 0; mi < 4; ++mi)
#pragma unroll
      for (int ni = 0; ni < 4; ++ni)
        acc[mi][ni] = __builtin_amdgcn_mfma_f32_16x16x32_bf16(af[mi], bfr[ni],
                                                              acc[mi][ni], 0, 0, 0);
  }
#undef STAGE

  const int m_base = tm * 128 + wr * 64;
  const int n_base = tn * 128 + wc * 64;
  if (MODE == 1) {
#pragma unroll
    for (int mi = 0; mi < 4; ++mi) {
#pragma unroll
      for (int r = 0; r < 4; ++r) {
        int row = m_base + mi * 16 + lkhi * 4 + r;
        int id = vid[row];
#pragma unroll
        for (int ni = 0; ni < 4; ++ni) {
          int col = n_base + ni * 16 + lrow;
          float v = acc[mi][ni][r] + bias[col];
          v = v > 0.f ? v : LEAKY * v;
          float hv = hst[(size_t)row * HD + col];
          float fh = (id >= 0) ? hv + v : hv;
          outf[(size_t)row * HD + col] = fh;                       // f32 final_h
          outb[(size_t)row * ldo + col_off + col] = f2bf(fh);      // bf16 for LSTM GEMM
        }
      }
    }
  } else if (MODE == 3) {
    const bool real = rsp[0] != 0;
    const int hcol = tn * 32 + wc * 16 + lrow;
    const float bi = bias[hcol];
    const float bff = bias[256 + hcol];
    const float bg = bias[512 + hcol];
    const float bo = bias[768 + hcol];
    float* outs = outf;
    float* houtp = outf + (size_t)NB * HD;
    float* coutp = outf + (size_t)2 * NB * HD;
#pragma unroll
    for (int mi = 0; mi < 4; ++mi) {
#pragma unroll
      for (int r = 0; r < 4; ++r) {
        int row = m_base + mi * 16 + lkhi * 4 + r;
        size_t base = (size_t)row * HD + hcol;
        float cold = cin[base];
        float i_ = sigm(acc[mi][0][r] + bi);
        float f_ = sigm(acc[mi][1][r] + bff);
        float g_ = tanha(acc[mi][2][r] + bg);
        float o_ = sigm(acc[mi][3][r] + bo);
        float cv = f_ * cold + i_ * g_;
        float hv = o_ * tanha(cv);
        outs[base] = hv;
        if (real) {
          houtp[base] = hv;       // else: final_h already written by MODE1
          coutp[base] = cv;
        } else {
          coutp[base] = cold;
        }
      }
    }
  } else {  // MODE 0
#pragma unroll
    for (int ni = 0; ni < 4; ++ni) {
      int col = n_base + ni * 16 + lrow;
      float bia = bias[col];
#pragma unroll
      for (int mi = 0; mi < 4; ++mi) {
#pragma unroll
        for (int r = 0; r < 4; ++r) {
          int row = m_base + mi * 16 + lkhi * 4 + r;
          float v = acc[mi][ni][r] + bia;
          v = v > 0.f ? v : LEAKY * v;
          outb[(size_t)row * ldo + col_off + col] = f2bf(v);
        }
      }
    }
  }
}

// ---------------- launch ----------------
extern "C" void kernel_launch(void* const* d_in, const int* in_sizes, int n_in,
                              void* d_out, int out_size, void* d_ws, size_t ws_size,
                              hipStream_t stream) {
  const float* x = (const float*)d_in[0];
  const int* vid = (const int*)d_in[1];
  const unsigned char* rs = (const unsigned char*)d_in[2];
  const float* h = (const float*)d_in[3];
  const float* c = (const float*)d_in[4];
  const float* W1 = (const float*)d_in[5];
  const float* b1 = (const float*)d_in[6];
  const float* W2 = (const float*)d_in[7];
  const float* b2 = (const float*)d_in[8];
  const float* W3 = (const float*)d_in[9];
  const float* b3 = (const float*)d_in[10];
  const float* Wk = (const float*)d_in[11];
  const float* Wr = (const float*)d_in[12];
  const float* bl = (const float*)d_in[13];
  float* dout = (float*)d_out;

  char* ws = (char*)d_ws;
  unsigned short* W1t = (unsigned short*)(ws);                         // 512x512 bf16
  unsigned short* W2t = (unsigned short*)(ws + 524288);                // 512x512
  unsigned short* W3t = (unsigned short*)(ws + 1048576);               // 256x512
  unsigned short* Wkrt = (unsigned short*)(ws + 1310720);              // 1024x512
  unsigned short* bufA = (unsigned short*)(ws + 2359296);              // [B,512] bf16
  unsigned short* bufB = (unsigned short*)(ws + 2359296 + 33554432);   // [B,512] bf16
  unsigned short* catb = (unsigned short*)(ws + 2359296 + 67108864);   // [B,512] bf16

  float* fhout = dout + (size_t)NB * HD;  // h_out slot doubles as f32 final_h

  wprep<<<288, 256, 0, stream>>>(W1, W2, W3, Wk, Wr, W1t, W2t, W3t, Wkrt);
  build_rows<<<NB * 32 / 256, 256, 0, stream>>>(x, h, vid, catb, bufA);

  // L1: bufB = leaky(cs0 @ W1 + b1)
  gemm_bk32<0, 4><<<(NB / 128) * 4, 256, 0, stream>>>(
      bufA, W1t, b1, bufB, 512, 0, nullptr, nullptr, nullptr, nullptr, nullptr);
  // L2: bufA = leaky(a1 @ W2 + b2)
  gemm_bk32<0, 4><<<(NB / 128) * 4, 256, 0, stream>>>(
      bufB, W2t, b2, bufA, 512, 0, nullptr, nullptr, nullptr, nullptr, nullptr);
  // L3: cs = leaky(a2 @ W3 + b3); final_h = h + cs (vid>=0) -> fhout f32 + catb[:,256:]
  gemm_bk32<1, 2><<<(NB / 128) * 2, 256, 0, stream>>>(
      bufA, W3t, b3, catb, 512, 256, fhout, h, vid, nullptr, nullptr);
  // LSTM: z = [x, fh] @ Wkrt^T + bl, gates fused in-register -> outputs/h_out/c_out
  gemm_bk32<3, 8><<<(NB / 128) * 8, 256, 0, stream>>>(
      catb, Wkrt, bl, nullptr, 0, 0, dout, nullptr, nullptr, c, rs);
}

// Round 10
// 341.090 us; speedup vs baseline: 1.1037x; 1.0649x over previous
//
#include <hip/hip_runtime.h>
#include <stdint.h>

#define LEAKY 0.2f
#define NB 32768
#define HD 256

typedef __attribute__((ext_vector_type(8))) short short8;
typedef __attribute__((ext_vector_type(8))) unsigned short ushort8;
typedef __attribute__((ext_vector_type(4))) float f4;

static __device__ __forceinline__ float bf2f(unsigned short u) {
  union { unsigned int i; float f; } v; v.i = ((unsigned int)u) << 16; return v.f;
}
static __device__ __forceinline__ unsigned short f2bf(float f) {
  union { float f; unsigned int i; } v; v.f = f;
  return (unsigned short)((v.i + 0x7fffu + ((v.i >> 16) & 1u)) >> 16);  // RNE
}
static __device__ __forceinline__ ushort8 pack8(f4 a, f4 b) {
  ushort8 o;
  o[0] = f2bf(a[0]); o[1] = f2bf(a[1]); o[2] = f2bf(a[2]); o[3] = f2bf(a[3]);
  o[4] = f2bf(b[0]); o[5] = f2bf(b[1]); o[6] = f2bf(b[2]); o[7] = f2bf(b[3]);
  return o;
}
static __device__ __forceinline__ float sigm(float x) { return 1.f / (1.f + __expf(-x)); }
static __device__ __forceinline__ float tanha(float x) {
  float e = __expf(2.f * x);
  return 1.f - 2.f / (e + 1.f);   // finite for e -> inf
}

__device__ __forceinline__ void gload16(const void* g, void* s) {
  __builtin_amdgcn_global_load_lds(
      (const __attribute__((address_space(1))) unsigned int*)g,
      (__attribute__((address_space(3))) unsigned int*)s, 16, 0, 0);
}

// ---------------- weight prep: LDS-tiled transpose, 1 launch ----------------
__global__ void wprep(const float* __restrict__ W1, const float* __restrict__ W2,
                      const float* __restrict__ W3, const float* __restrict__ Wk,
                      const float* __restrict__ Wr,
                      unsigned short* __restrict__ W1t, unsigned short* __restrict__ W2t,
                      unsigned short* __restrict__ W3t, unsigned short* __restrict__ Wkrt) {
  __shared__ float tile[64][65];
  const int id = blockIdx.x, t = threadIdx.x;
  const int tr = t >> 6, tc = t & 63;   // 4 rows per pass, 16 passes

  const float* src;
  unsigned short* dst;
  int kbase, nbase, srcld, perm = 0;
  if (id < 64) {
    src = W1; dst = W1t; srcld = 512;
    kbase = (id >> 3) * 64; nbase = (id & 7) * 64;
  } else if (id < 128) {
    src = W2; dst = W2t; srcld = 512;
    kbase = ((id - 64) >> 3) * 64; nbase = ((id - 64) & 7) * 64;
  } else if (id < 160) {
    src = W3; dst = W3t; srcld = 256;
    kbase = ((id - 128) >> 2) * 64; nbase = ((id - 128) & 3) * 64;
  } else {
    src = nullptr; dst = Wkrt; srcld = 1024; perm = 1;
    kbase = ((id - 160) >> 4) * 64; nbase = ((id - 160) & 15) * 64;
  }

#pragma unroll
  for (int p = 0; p < 16; ++p) {
    int r = p * 4 + tr;             // k offset within tile
    int k = kbase + r, n = nbase + tc;
    float v;
    if (perm) {
      v = (k < 256) ? Wk[k * 1024 + n] : Wr[(k - 256) * 1024 + n];
    } else {
      v = src[k * srcld + n];
    }
    tile[r][tc] = v;
  }
  __syncthreads();
#pragma unroll
  for (int p = 0; p < 16; ++p) {
    int c = p * 4 + tr;             // n offset within tile
    int n = nbase + c;
    int orow;
    if (perm) {
      int gate = n >> 8, hcol = n & 255;
      orow = (hcol >> 5) * 128 + ((hcol >> 4) & 1) * 64 + gate * 16 + (hcol & 15);
    } else {
      orow = n;
    }
    dst[orow * 512 + kbase + tc] = f2bf(tile[tc][c]);
  }
}

// catb[:, :256] = bf16(x); csb[:, :256] = bf16(h); csb[:, 256:] = bf16(gather(h, vid))
__global__ void build_rows(const float* __restrict__ x, const float* __restrict__ h,
                           const int* __restrict__ vid,
                           unsigned short* __restrict__ catb,
                           unsigned short* __restrict__ csb) {
  int idx = blockIdx.x * 256 + threadIdx.x;   // NB*32 threads, 8 elems each
  int m = idx >> 5;
  int j = (idx & 31) << 3;
  f4 a0 = *(const f4*)(x + (size_t)m * 256 + j);
  f4 a1 = *(const f4*)(x + (size_t)m * 256 + j + 4);
  *(ushort8*)(catb + (size_t)m * 512 + j) = pack8(a0, a1);
  f4 h0 = *(const f4*)(h + (size_t)m * 256 + j);
  f4 h1 = *(const f4*)(h + (size_t)m * 256 + j + 4);
  *(ushort8*)(csb + (size_t)m * 512 + j) = pack8(h0, h1);
  int id = vid[m];
  f4 g0 = {0.f, 0.f, 0.f, 0.f}, g1 = {0.f, 0.f, 0.f, 0.f};
  if (id >= 0) {
    g0 = *(const f4*)(h + (size_t)id * 256 + j);
    g1 = *(const f4*)(h + (size_t)id * 256 + j + 4);
  }
  *(ushort8*)(csb + (size_t)m * 512 + 256 + j) = pack8(g0, g1);
}

// -------- 256x128-tile GEMM (round-4 sync structure, bigger M-tile) --------
// epilogue(A[M,512] @ Bt[N,512]^T + bias). 512 thr / 8 waves (4M x 2N), wave 64x64.
// Same proven K-loop as round 4: stage -> __syncthreads -> ds+MFMA -> __syncthreads.
// Staging: 48 KB/K-tile for a 2x larger C-tile (-25% bytes/output); 6 gload16/thr.
// LDS 48 KB -> 2-3 blocks/CU keeps cross-block overlap (round-7/8 lesson).
// MODE 0: leaky -> bf16. MODE 1: leaky + final_h -> f32 + bf16. MODE 3: fused LSTM.
template <int MODE, int NTN>
__global__ __launch_bounds__(512, 4) void gemm_bm256(
    const unsigned short* __restrict__ A,   // [M, 512] bf16 row-major
    const unsigned short* __restrict__ Bt,  // [N, 512] bf16 row-major
    const float* __restrict__ bias,
    unsigned short* __restrict__ outb, int ldo, int col_off,
    float* __restrict__ outf,               // MODE1: f32 final_h; MODE3: d_out base
    const float* __restrict__ hst,          // MODE1: h
    const int* __restrict__ vid,            // MODE1
    const float* __restrict__ cin,          // MODE3: c
    const unsigned char* __restrict__ rsp) {// MODE3: real_step
  __shared__ unsigned short sA[256 * 64];   // 32 KB, 8 x 16B slots/row, XOR-swizzled
  __shared__ unsigned short sB[128 * 64];   // 16 KB

  const int t = threadIdx.x;
  const int p = blockIdx.x;
  const int xcd = p & 7, local = p >> 3;
  const int tm = xcd + ((local / NTN) << 3);   // T1: col-tiles of a row-tile share an XCD
  const int tn = local % NTN;
  const int wid = t >> 6, lane = t & 63;
  const int wr = wid >> 1, wc = wid & 1;       // 4x2 waves -> 64x64 each
  const int lrow = lane & 15, lkhi = lane >> 4;
  const int rr = t >> 3, slot = t & 7;         // staging: row 0..63 + 64*i, 16B slot

  const unsigned short* Asrc = A + (size_t)tm * 256 * 512;
  const unsigned short* Bsrc = Bt + (size_t)tn * 128 * 512;

  f4 acc[4][4];
#pragma unroll
  for (int i = 0; i < 4; ++i)
#pragma unroll
    for (int j = 0; j < 4; ++j) acc[i][j] = {0.f, 0.f, 0.f, 0.f};

  for (int k0 = 0; k0 < 512; k0 += 64) {
    // stage 256x64 A + 128x64 B; linear LDS dest, inverse-swizzled global src (G21)
#pragma unroll
    for (int i = 0; i < 4; ++i) {
      int r = i * 64 + rr;
      int gs = slot ^ (r & 7);
      gload16(Asrc + (size_t)r * 512 + k0 + gs * 8, (char*)sA + r * 128 + slot * 16);
    }
#pragma unroll
    for (int i = 0; i < 2; ++i) {
      int r = i * 64 + rr;
      int gs = slot ^ (r & 7);
      gload16(Bsrc + (size_t)r * 512 + k0 + gs * 8, (char*)sB + r * 128 + slot * 16);
    }
    __syncthreads();   // drains vmcnt (global_load_lds) + barrier
#pragma unroll
    for (int kk = 0; kk < 2; ++kk) {
      short8 af[4], bfr[4];
#pragma unroll
      for (int mi = 0; mi < 4; ++mi) {
        int row = wr * 64 + mi * 16 + lrow;
        int s = (kk * 4 + lkhi) ^ (row & 7);
        af[mi] = *(const short8*)&sA[row * 64 + s * 8];
      }
#pragma unroll
      for (int ni = 0; ni < 4; ++ni) {
        int rn = wc * 64 + ni * 16 + lrow;
        int s = (kk * 4 + lkhi) ^ (rn & 7);
        bfr[ni] = *(const short8*)&sB[rn * 64 + s * 8];
      }
#pragma unroll
      for (int mi = 0; mi < 4; ++mi)
#pragma unroll
        for (int ni = 0; ni < 4; ++ni)
          acc[mi][ni] = __builtin_amdgcn_mfma_f32_16x16x32_bf16(af[mi], bfr[ni],
                                                                acc[mi][ni], 0, 0, 0);
    }
    __syncthreads();
  }

  const int m_base = tm * 256 + wr * 64;
  const int n_base = tn * 128 + wc * 64;
  if (MODE == 1) {
#pragma unroll
    for (int mi = 0; mi < 4; ++mi) {
#pragma unroll
      for (int r = 0; r < 4; ++r) {
        int row = m_base + mi * 16 + lkhi * 4 + r;
        int id = vid[row];
#pragma unroll
        for (int ni = 0; ni < 4; ++ni) {
          int col = n_base + ni * 16 + lrow;
          float v = acc[mi][ni][r] + bias[col];
          v = v > 0.f ? v : LEAKY * v;
          float hv = hst[(size_t)row * HD + col];
          float fh = (id >= 0) ? hv + v : hv;
          outf[(size_t)row * HD + col] = fh;                       // f32 final_h
          outb[(size_t)row * ldo + col_off + col] = f2bf(fh);      // bf16 for LSTM GEMM
        }
      }
    }
  } else if (MODE == 3) {
    const bool real = rsp[0] != 0;
    const int hcol = tn * 32 + wc * 16 + lrow;   // gate==ni under Wkrt interleave
    const float bi = bias[hcol];
    const float bff = bias[256 + hcol];
    const float bg = bias[512 + hcol];
    const float bo = bias[768 + hcol];
    float* outs = outf;
    float* houtp = outf + (size_t)NB * HD;
    float* coutp = outf + (size_t)2 * NB * HD;
#pragma unroll
    for (int mi = 0; mi < 4; ++mi) {
#pragma unroll
      for (int r = 0; r < 4; ++r) {
        int row = m_base + mi * 16 + lkhi * 4 + r;
        size_t base = (size_t)row * HD + hcol;
        float cold = cin[base];
        float i_ = sigm(acc[mi][0][r] + bi);
        float f_ = sigm(acc[mi][1][r] + bff);
        float g_ = tanha(acc[mi][2][r] + bg);
        float o_ = sigm(acc[mi][3][r] + bo);
        float cv = f_ * cold + i_ * g_;
        float hv = o_ * tanha(cv);
        outs[base] = hv;
        if (real) {
          houtp[base] = hv;       // else: final_h already written by MODE1
          coutp[base] = cv;
        } else {
          coutp[base] = cold;
        }
      }
    }
  } else {  // MODE 0
#pragma unroll
    for (int ni = 0; ni < 4; ++ni) {
      int col = n_base + ni * 16 + lrow;
      float bia = bias[col];
#pragma unroll
      for (int mi = 0; mi < 4; ++mi) {
#pragma unroll
        for (int r = 0; r < 4; ++r) {
          int row = m_base + mi * 16 + lkhi * 4 + r;
          float v = acc[mi][ni][r] + bia;
          v = v > 0.f ? v : LEAKY * v;
          outb[(size_t)row * ldo + col_off + col] = f2bf(v);
        }
      }
    }
  }
}

// ---------------- launch ----------------
extern "C" void kernel_launch(void* const* d_in, const int* in_sizes, int n_in,
                              void* d_out, int out_size, void* d_ws, size_t ws_size,
                              hipStream_t stream) {
  const float* x = (const float*)d_in[0];
  const int* vid = (const int*)d_in[1];
  const unsigned char* rs = (const unsigned char*)d_in[2];
  const float* h = (const float*)d_in[3];
  const float* c = (const float*)d_in[4];
  const float* W1 = (const float*)d_in[5];
  const float* b1 = (const float*)d_in[6];
  const float* W2 = (const float*)d_in[7];
  const float* b2 = (const float*)d_in[8];
  const float* W3 = (const float*)d_in[9];
  const float* b3 = (const float*)d_in[10];
  const float* Wk = (const float*)d_in[11];
  const float* Wr = (const float*)d_in[12];
  const float* bl = (const float*)d_in[13];
  float* dout = (float*)d_out;

  char* ws = (char*)d_ws;
  unsigned short* W1t = (unsigned short*)(ws);                         // 512x512 bf16
  unsigned short* W2t = (unsigned short*)(ws + 524288);                // 512x512
  unsigned short* W3t = (unsigned short*)(ws + 1048576);               // 256x512
  unsigned short* Wkrt = (unsigned short*)(ws + 1310720);              // 1024x512
  unsigned short* bufA = (unsigned short*)(ws + 2359296);              // [B,512] bf16
  unsigned short* bufB = (unsigned short*)(ws + 2359296 + 33554432);   // [B,512] bf16
  unsigned short* catb = (unsigned short*)(ws + 2359296 + 67108864);   // [B,512] bf16

  float* fhout = dout + (size_t)NB * HD;  // h_out slot doubles as f32 final_h

  wprep<<<288, 256, 0, stream>>>(W1, W2, W3, Wk, Wr, W1t, W2t, W3t, Wkrt);
  build_rows<<<NB * 32 / 256, 256, 0, stream>>>(x, h, vid, catb, bufA);

  // L1: bufB = leaky(cs0 @ W1 + b1)
  gemm_bm256<0, 4><<<(NB / 256) * 4, 512, 0, stream>>>(
      bufA, W1t, b1, bufB, 512, 0, nullptr, nullptr, nullptr, nullptr, nullptr);
  // L2: bufA = leaky(a1 @ W2 + b2)
  gemm_bm256<0, 4><<<(NB / 256) * 4, 512, 0, stream>>>(
      bufB, W2t, b2, bufA, 512, 0, nullptr, nullptr, nullptr, nullptr, nullptr);
  // L3: cs = leaky(a2 @ W3 + b3); final_h = h + cs (vid>=0) -> fhout f32 + catb[:,256:]
  gemm_bm256<1, 2><<<(NB / 256) * 2, 512, 0, stream>>>(
      bufA, W3t, b3, catb, 512, 256, fhout, h, vid, nullptr, nullptr);
  // LSTM: z = [x, fh] @ Wkrt^T + bl, gates fused in-register -> outputs/h_out/c_out
  gemm_bm256<3, 8><<<(NB / 256) * 8, 512, 0, stream>>>(
      catb, Wkrt, bl, nullptr, 0, 0, dout, nullptr, nullptr, c, rs);
}